// Round 2
// baseline (809.154 us; speedup 1.0000x reference)
//
#include <hip/hip_runtime.h>
#include <stdint.h>

typedef unsigned short u16;
typedef __attribute__((ext_vector_type(8))) short bf16x8;
typedef __attribute__((ext_vector_type(4))) float f32x4;

#define AS1C(p) ((const __attribute__((address_space(1))) char*)(const char*)(p))
#define AS3C(p) ((__attribute__((address_space(3))) char*)(char*)(p))

static __device__ __forceinline__ u16 f2bf(float f) {
  uint32_t u = __builtin_bit_cast(uint32_t, f);
  u = (u + 0x7FFFu + ((u >> 16) & 1u)) >> 16;
  return (u16)u;
}

// ---------------- fp32 -> bf16 conversion ----------------
__global__ __launch_bounds__(256) void k_f2bf(const float* __restrict__ src,
                                              u16* __restrict__ dst, int n4) {
  int i = blockIdx.x * blockDim.x + threadIdx.x;
  if (i >= n4) return;
  float4 v = reinterpret_cast<const float4*>(src)[i];
  ushort4 o;
  o.x = f2bf(v.x); o.y = f2bf(v.y); o.z = f2bf(v.z); o.w = f2bf(v.w);
  reinterpret_cast<ushort4*>(dst)[i] = o;
}

// ---------------- GEMM: C[M,N] = act(A[M,K] * B[N,K]^T + bias) ----------------
// 128x128 tile, 4 waves (2x2), BK=32, global_load_lds staging (m97 structure)
template<bool OUT_BF16, bool RELU>
__global__ __launch_bounds__(256) void k_gemm(const u16* __restrict__ A,
                                              const u16* __restrict__ B,
                                              const float* __restrict__ bias,
                                              void* __restrict__ C,
                                              int M, int N, int K) {
  __shared__ __align__(16) char As[8192];
  __shared__ __align__(16) char Bs[8192];
  const int tid  = threadIdx.x;
  const int lane = tid & 63;
  const int wid  = tid >> 6;
  const int wm = wid >> 1, wn = wid & 1;
  const long bm = (long)blockIdx.y * 128, bn = (long)blockIdx.x * 128;

  // staging chunk geometry: rows are 64B (32 bf16); two 1KB chunks per wave
  const int o0 = wid * 2048 + lane * 16;
  const int o1 = o0 + 1024;
  const int r0 = o0 >> 6, kb0 = o0 & 63;
  const int r1 = o1 >> 6, kb1 = o1 & 63;
  const unsigned l0 = (unsigned)__builtin_amdgcn_readfirstlane(wid * 2048);
  const unsigned l1 = l0 + 1024;
  const char* Ab = (const char*)A;
  const char* Bb = (const char*)B;

  f32x4 acc[4][4];
#pragma unroll
  for (int i = 0; i < 4; i++)
#pragma unroll
    for (int j = 0; j < 4; j++) acc[i][j] = 0.f;

  const int nK = K >> 5;
  for (int kt = 0; kt < nK; ++kt) {
    const long k0 = (long)kt * 32;
    __builtin_amdgcn_global_load_lds(AS1C(Ab + ((bm + r0) * K + k0) * 2 + kb0), AS3C(As + l0), 16, 0, 0);
    __builtin_amdgcn_global_load_lds(AS1C(Ab + ((bm + r1) * K + k0) * 2 + kb1), AS3C(As + l1), 16, 0, 0);
    __builtin_amdgcn_global_load_lds(AS1C(Bb + ((bn + r0) * K + k0) * 2 + kb0), AS3C(Bs + l0), 16, 0, 0);
    __builtin_amdgcn_global_load_lds(AS1C(Bb + ((bn + r1) * K + k0) * 2 + kb1), AS3C(Bs + l1), 16, 0, 0);
    __syncthreads();
    bf16x8 af[4], bfr[4];
#pragma unroll
    for (int i = 0; i < 4; i++) {
      af[i]  = *reinterpret_cast<const bf16x8*>(As + (wm * 64 + i * 16 + (lane & 15)) * 64 + (lane >> 4) * 16);
      bfr[i] = *reinterpret_cast<const bf16x8*>(Bs + (wn * 64 + i * 16 + (lane & 15)) * 64 + (lane >> 4) * 16);
    }
#pragma unroll
    for (int i = 0; i < 4; i++)
#pragma unroll
      for (int j = 0; j < 4; j++)
        acc[i][j] = __builtin_amdgcn_mfma_f32_16x16x32_bf16(af[i], bfr[j], acc[i][j], 0, 0, 0);
    __syncthreads();
  }

  u16* Cb = (u16*)C;
  float* Cf = (float*)C;
#pragma unroll
  for (int j = 0; j < 4; j++) {
    const long col = bn + wn * 64 + j * 16 + (lane & 15);
    const float bv = bias[col];
#pragma unroll
    for (int i = 0; i < 4; i++) {
      const long rbase = bm + wm * 64 + i * 16 + (lane >> 4) * 4;
#pragma unroll
      for (int q = 0; q < 4; q++) {
        float v = acc[i][j][q] + bv;
        if (RELU) v = fmaxf(v, 0.f);
        if (OUT_BF16) Cb[(rbase + q) * N + col] = f2bf(v);
        else          Cf[(rbase + q) * N + col] = v;
      }
    }
  }
}

// ---------------- V transpose: qkv V-block -> vt[g][h][c(64)][n(512)] ----------------
__global__ __launch_bounds__(256) void k_transpose_v(const u16* __restrict__ qkv,
                                                     u16* __restrict__ vt) {
  const int gh = blockIdx.x, g = gh >> 4, h = gh & 15;
  const int tid = threadIdx.x;
  __shared__ __align__(16) u16 tile[4096]; // [n(64)][c(64)] chunk-swizzled
  for (int nt = 0; nt < 8; ++nt) {
    const int n0 = nt * 64;
#pragma unroll
    for (int c = 0; c < 2; ++c) {
      const int ch = tid * 2 + c;           // 0..511
      const int n = ch >> 3;                // 0..63
      const int cc = ch & 7;                // logical 8-elem chunk in c-dim
      const uint4 v = *reinterpret_cast<const uint4*>(
          qkv + (long)(g * 512 + n0 + n) * 3072 + 2048 + h * 64 + cc * 8);
      const int phys = cc ^ (n & 7) ^ (n >> 3);
      *reinterpret_cast<uint4*>(tile + n * 64 + phys * 8) = v;
    }
    __syncthreads();
#pragma unroll
    for (int c = 0; c < 2; ++c) {
      const int ch = tid * 2 + c;
      const int crow = ch >> 3;             // head-col index 0..63
      const int noff = (ch & 7) * 8;
      union { u16 s[8]; uint4 u; } val;
#pragma unroll
      for (int i = 0; i < 8; ++i) {
        const int n = noff + i;
        const int phys = (crow >> 3) ^ (n & 7) ^ (n >> 3);
        val.s[i] = tile[n * 64 + phys * 8 + (crow & 7)];
      }
      *reinterpret_cast<uint4*>(vt + (long)(gh * 64 + crow) * 512 + n0 + noff) = val.u;
    }
    __syncthreads();
  }
}

// ---------------- fused attention ----------------
// grid: (8 q-blocks, 16 heads, 32 graphs), 256 threads (4 waves x 16 Q rows)
__global__ __launch_bounds__(256) void k_attn(const u16* __restrict__ qkv,
                                              const u16* __restrict__ vt,
                                              u16* __restrict__ out) {
  __shared__ __align__(16) char Ks[8192];       // [kvrow(64)][128B], chunk-XOR swizzled
  __shared__ __align__(16) char Vs[8192];       // [c(64)][128B kv], chunk-XOR swizzled
  __shared__ __align__(16) char Ps[4][2048];    // per-wave P [16][128B], swizzled
  const int tid = threadIdx.x, lane = tid & 63, wid = tid >> 6;
  const int qb = blockIdx.x, h = blockIdx.y, g = blockIdx.z;
  const int gh = g * 16 + h;
  const long grow0 = (long)g * 512;
  const char* qbase = (const char*)qkv;

  // Q fragments (row = lane&15 of this wave's 16-row strip)
  const long qrow = qb * 64 + wid * 16 + (lane & 15);
  bf16x8 qf[2];
#pragma unroll
  for (int kf = 0; kf < 2; ++kf) {
    const long go = (((grow0 + qrow) * 3072) + h * 64 + kf * 32 + (lane >> 4) * 8) * 2;
    qf[kf] = *reinterpret_cast<const bf16x8*>(qbase + go);
  }

  f32x4 oacc[4];
#pragma unroll
  for (int i = 0; i < 4; i++) oacc[i] = 0.f;
  float mrun[4], lrun[4];
#pragma unroll
  for (int q = 0; q < 4; q++) { mrun[q] = -3.0e38f; lrun[q] = 0.f; }

  const unsigned l0 = (unsigned)__builtin_amdgcn_readfirstlane(wid * 2048);
  const unsigned l1 = l0 + 1024;

  for (int it = 0; it < 8; ++it) {
    const int kv0 = it * 64;
    // stage K tile and V tile (source-side XOR swizzle, linear LDS dest)
#pragma unroll
    for (int c = 0; c < 2; ++c) {
      const int o = wid * 2048 + c * 1024 + lane * 16;
      const int row = o >> 7;
      const int pch = (o >> 4) & 7;
      const int lch = pch ^ (row & 7);
      const long gK = (((grow0 + kv0 + row) * 3072) + 1024 + h * 64 + lch * 8) * 2;
      __builtin_amdgcn_global_load_lds(AS1C(qbase + gK), AS3C(Ks + (c ? l1 : l0)), 16, 0, 0);
      const long gV = (((long)(gh * 64 + row)) * 512 + kv0 + lch * 8) * 2;
      __builtin_amdgcn_global_load_lds(AS1C((const char*)vt + gV), AS3C(Vs + (c ? l1 : l0)), 16, 0, 0);
    }
    __syncthreads();

    // S = Q K^T / 8  (4 tiles of 16 kv cols)
    f32x4 s[4];
#pragma unroll
    for (int nt = 0; nt < 4; ++nt) {
      const int krow = nt * 16 + (lane & 15);
      const int sw = krow & 7;
      const bf16x8 k0 = *reinterpret_cast<const bf16x8*>(Ks + krow * 128 + (((lane >> 4)) ^ sw) * 16);
      const bf16x8 k1 = *reinterpret_cast<const bf16x8*>(Ks + krow * 128 + (((lane >> 4) + 4) ^ sw) * 16);
      f32x4 t = 0.f;
      t = __builtin_amdgcn_mfma_f32_16x16x32_bf16(qf[0], k0, t, 0, 0, 0);
      t = __builtin_amdgcn_mfma_f32_16x16x32_bf16(qf[1], k1, t, 0, 0, 0);
#pragma unroll
      for (int q = 0; q < 4; q++) t[q] *= 0.125f;
      s[nt] = t;
    }

    // online softmax update (rows owned: (lane>>4)*4+q; cols across 16 lanes)
    float tmax[4];
#pragma unroll
    for (int q = 0; q < 4; q++)
      tmax[q] = fmaxf(fmaxf(s[0][q], s[1][q]), fmaxf(s[2][q], s[3][q]));
#pragma unroll
    for (int d = 1; d < 16; d <<= 1)
#pragma unroll
      for (int q = 0; q < 4; q++) tmax[q] = fmaxf(tmax[q], __shfl_xor(tmax[q], d));
    float sf[4];
#pragma unroll
    for (int q = 0; q < 4; q++) {
      const float mn = fmaxf(mrun[q], tmax[q]);
      sf[q] = __expf(mrun[q] - mn);
      mrun[q] = mn;
    }
    float rs[4] = {0.f, 0.f, 0.f, 0.f};
#pragma unroll
    for (int nt = 0; nt < 4; nt++)
#pragma unroll
      for (int q = 0; q < 4; q++) {
        const float p = __expf(s[nt][q] - mrun[q]);
        s[nt][q] = p;
        rs[q] += p;
      }
#pragma unroll
    for (int d = 1; d < 16; d <<= 1)
#pragma unroll
      for (int q = 0; q < 4; q++) rs[q] += __shfl_xor(rs[q], d);
#pragma unroll
    for (int q = 0; q < 4; q++) lrun[q] = lrun[q] * sf[q] + rs[q];
#pragma unroll
    for (int i = 0; i < 4; i++)
#pragma unroll
      for (int q = 0; q < 4; q++) oacc[i][q] *= sf[q];

    // P (bf16) -> per-wave LDS, swizzled
    char* pw = Ps[wid];
#pragma unroll
    for (int nt = 0; nt < 4; nt++) {
      const int cc = nt * 16 + (lane & 15);
#pragma unroll
      for (int q = 0; q < 4; q++) {
        const int r = (lane >> 4) * 4 + q;
        const int phys = (cc >> 3) ^ (r & 7);
        *(u16*)(pw + r * 128 + phys * 16 + (cc & 7) * 2) = f2bf(s[nt][q]);
      }
    }

    // O += P V
#pragma unroll
    for (int kf = 0; kf < 2; ++kf) {
      const int prow = lane & 15;
      const bf16x8 pa = *reinterpret_cast<const bf16x8*>(
          pw + prow * 128 + ((kf * 4 + (lane >> 4)) ^ (prow & 7)) * 16);
#pragma unroll
      for (int ot = 0; ot < 4; ++ot) {
        const int vr = ot * 16 + (lane & 15);
        const bf16x8 vb = *reinterpret_cast<const bf16x8*>(
            Vs + vr * 128 + ((kf * 4 + (lane >> 4)) ^ (vr & 7)) * 16);
        oacc[ot] = __builtin_amdgcn_mfma_f32_16x16x32_bf16(pa, vb, oacc[ot], 0, 0, 0);
      }
    }
    __syncthreads();
  }

  // epilogue: O / l -> bf16
#pragma unroll
  for (int ot = 0; ot < 4; ++ot) {
    const int col = h * 64 + ot * 16 + (lane & 15);
#pragma unroll
    for (int q = 0; q < 4; q++) {
      const long r = grow0 + qb * 64 + wid * 16 + (lane >> 4) * 4 + q;
      out[r * 1024 + col] = f2bf(oacc[ot][q] / lrun[q]);
    }
  }
}

// ---------------- residual + layernorm ----------------
template<bool EMIT_BF16>
__global__ __launch_bounds__(256) void k_ln(const float* __restrict__ A,
                                            const float* __restrict__ Bz,
                                            const float* __restrict__ gam,
                                            const float* __restrict__ bet,
                                            float* __restrict__ out_f,
                                            u16* __restrict__ out_b) {
  const int row = blockIdx.x;
  const int tid = threadIdx.x;
  const long base = (long)row * 1024;
  const float4 a = reinterpret_cast<const float4*>(A + base)[tid];
  const float4 b = reinterpret_cast<const float4*>(Bz + base)[tid];
  const float x0 = a.x + b.x, x1 = a.y + b.y, x2 = a.z + b.z, x3 = a.w + b.w;
  float s1 = x0 + x1 + x2 + x3;
  float s2 = x0 * x0 + x1 * x1 + x2 * x2 + x3 * x3;
#pragma unroll
  for (int d = 1; d < 64; d <<= 1) { s1 += __shfl_xor(s1, d); s2 += __shfl_xor(s2, d); }
  __shared__ float red[8];
  const int wid = tid >> 6, lane = tid & 63;
  if (lane == 0) { red[wid] = s1; red[4 + wid] = s2; }
  __syncthreads();
  s1 = red[0] + red[1] + red[2] + red[3];
  s2 = red[4] + red[5] + red[6] + red[7];
  const float mu = s1 * (1.f / 1024.f);
  const float var = s2 * (1.f / 1024.f) - mu * mu;
  const float rstd = rsqrtf(var + 1e-5f);
  const float4 gv = reinterpret_cast<const float4*>(gam)[tid];
  const float4 bv = reinterpret_cast<const float4*>(bet)[tid];
  float4 y;
  y.x = (x0 - mu) * rstd * gv.x + bv.x;
  y.y = (x1 - mu) * rstd * gv.y + bv.y;
  y.z = (x2 - mu) * rstd * gv.z + bv.z;
  y.w = (x3 - mu) * rstd * gv.w + bv.w;
  reinterpret_cast<float4*>(out_f + base)[tid] = y;
  if (EMIT_BF16) {
    ushort4 o;
    o.x = f2bf(y.x); o.y = f2bf(y.y); o.z = f2bf(y.z); o.w = f2bf(y.w);
    reinterpret_cast<ushort4*>(out_b + base)[tid] = o;
  }
}

// ---------------- launcher ----------------
extern "C" void kernel_launch(void* const* d_in, const int* in_sizes, int n_in,
                              void* d_out, int out_size, void* d_ws, size_t ws_size,
                              hipStream_t stream) {
  const float* h    = (const float*)d_in[0];
  const float* w_in = (const float*)d_in[1];
  const float* b_in = (const float*)d_in[2];
  const float* w_o  = (const float*)d_in[3];
  const float* b_o  = (const float*)d_in[4];
  const float* ln1g = (const float*)d_in[5];
  const float* ln1b = (const float*)d_in[6];
  const float* ln2g = (const float*)d_in[7];
  const float* ln2b = (const float*)d_in[8];
  const float* w1   = (const float*)d_in[9];
  const float* b1   = (const float*)d_in[10];
  const float* w2   = (const float*)d_in[11];
  const float* b2   = (const float*)d_in[12];

  // Workspace map (total 184,549,376 B = 176 MB):
  //   [0,        33.5MB)  h_bf  -> attn_bf -> x1_bf   (sequential reuse)
  //   [33.5MB,   50.3MB)  weight bf16 copies
  //   [50.3MB,  151.0MB)  qkv   -> x1(fp32, first 67MB) + f1(bf16, next 67MB)
  //   [151.0MB, 176.0MB)  vt    -> (tail of f1)
  // d_out doubles as o32 (out-proj result) then f2 (FFN2 result); LN reads
  // its own row before writing, so in-place is safe.
  const size_t WS_NEED = 184549376;
  if (ws_size < WS_NEED) {
    // diagnostic fallback: zero output instead of faulting
    hipMemsetAsync(d_out, 0, (size_t)out_size * 4, stream);
    return;
  }

  char* W = (char*)d_ws;
  u16* h_bf     = (u16*)(W + 0);            // 33554432 B
  u16* w_in_bf  = (u16*)(W + 33554432);     // 6291456 B
  u16* w_out_bf = (u16*)(W + 39845888);     // 2097152 B
  u16* w1_bf    = (u16*)(W + 41943040);     // 4194304 B
  u16* w2_bf    = (u16*)(W + 46137344);     // 4194304 B
  u16* qkv      = (u16*)(W + 50331648);     // 100663296 B (dead after attn)
  u16* vt       = (u16*)(W + 150994944);    // 33554432 B  (dead after attn)
  float* x1     = (float*)(W + 50331648);   // 67108864 B (reuses qkv[0:67MB))
  u16* f1       = (u16*)(W + 117440512);    // 67108864 B (reuses qkv tail + vt)
  u16* attn_bf  = h_bf;
  u16* x1_bf    = h_bf;
  float* o32    = (float*)d_out;
  float* f2     = (float*)d_out;

  // bf16 conversions
  k_f2bf<<<dim3(16384), 256, 0, stream>>>(h, h_bf, 4194304);
  k_f2bf<<<dim3(3072),  256, 0, stream>>>(w_in, w_in_bf, 786432);
  k_f2bf<<<dim3(1024),  256, 0, stream>>>(w_o, w_out_bf, 262144);
  k_f2bf<<<dim3(2048),  256, 0, stream>>>(w1, w1_bf, 524288);
  k_f2bf<<<dim3(2048),  256, 0, stream>>>(w2, w2_bf, 524288);

  // qkv = h @ w_in^T + b_in   [16384, 3072] bf16
  k_gemm<true, false><<<dim3(24, 128), 256, 0, stream>>>(h_bf, w_in_bf, b_in, (void*)qkv, 16384, 3072, 1024);
  // V transpose for attention B-operand
  k_transpose_v<<<dim3(512), 256, 0, stream>>>(qkv, vt);
  // fused attention -> attn_bf [16384, 1024] bf16
  k_attn<<<dim3(8, 16, 32), 256, 0, stream>>>(qkv, vt, attn_bf);
  // o = attn @ w_out^T + b_out  [16384, 1024] fp32 -> d_out (scratch use)
  k_gemm<false, false><<<dim3(8, 128), 256, 0, stream>>>(attn_bf, w_out_bf, b_o, (void*)o32, 16384, 1024, 1024);
  // x1 = LN(h + o); also emit x1 as bf16 for FFN
  k_ln<true><<<dim3(16384), 256, 0, stream>>>(h, o32, ln1g, ln1b, x1, x1_bf);
  // f1 = relu(x1 @ w1^T + b1)  [16384, 2048] bf16
  k_gemm<true, true><<<dim3(16, 128), 256, 0, stream>>>(x1_bf, w1_bf, b1, (void*)f1, 16384, 2048, 1024);
  // f2 = f1 @ w2^T + b2        [16384, 1024] fp32 -> d_out (scratch use)
  k_gemm<false, false><<<dim3(8, 128), 256, 0, stream>>>(f1, w2_bf, b2, (void*)f2, 16384, 1024, 2048);
  // out = LN(x1 + f2)  (in-place on d_out)
  k_ln<false><<<dim3(16384), 256, 0, stream>>>(x1, f2, ln2g, ln2b, (float*)d_out, (u16*)nullptr);
}

// Round 3
// 684.702 us; speedup vs baseline: 1.1818x; 1.1818x over previous
//
#include <hip/hip_runtime.h>
#include <stdint.h>

typedef unsigned short u16;
typedef __attribute__((ext_vector_type(8))) short bf16x8;
typedef __attribute__((ext_vector_type(4))) float f32x4;

#define AS1C(p) ((const __attribute__((address_space(1))) char*)(const char*)(p))
#define AS3C(p) ((__attribute__((address_space(3))) char*)(char*)(p))

static __device__ __forceinline__ u16 f2bf(float f) {
  uint32_t u = __builtin_bit_cast(uint32_t, f);
  u = (u + 0x7FFFu + ((u >> 16) & 1u)) >> 16;
  return (u16)u;
}

// ---------------- fp32 -> bf16 conversion ----------------
__global__ __launch_bounds__(256) void k_f2bf(const float* __restrict__ src,
                                              u16* __restrict__ dst, int n4) {
  int i = blockIdx.x * blockDim.x + threadIdx.x;
  if (i >= n4) return;
  float4 v = reinterpret_cast<const float4*>(src)[i];
  ushort4 o;
  o.x = f2bf(v.x); o.y = f2bf(v.y); o.z = f2bf(v.z); o.w = f2bf(v.w);
  reinterpret_cast<ushort4*>(dst)[i] = o;
}

// =============== 256x256 8-phase GEMM (T1+T2+T3+T4+T5) ===============
// C[M,N] = act(A[M,K] * B[N,K]^T + bias).  8 waves (2M x 4N), BK=64,
// double-buffered 128KiB LDS, counted vmcnt(4), XOR-swizzled LDS reads
// with inverse-swizzled global staging sources (linear gload_lds dests).
#define BAR()  do { asm volatile("" ::: "memory"); __builtin_amdgcn_s_barrier(); asm volatile("" ::: "memory"); } while (0)
#define WLG()  asm volatile("s_waitcnt lgkmcnt(0)" ::: "memory")
#define WV4()  asm volatile("s_waitcnt vmcnt(4)" ::: "memory")

template<bool OUT_BF16, bool RELU>
__global__ __launch_bounds__(512, 2) void k_gemm256(const u16* __restrict__ A,
                                                    const u16* __restrict__ B,
                                                    const float* __restrict__ bias,
                                                    void* __restrict__ C,
                                                    int M, int N, int K) {
  __shared__ __align__(16) char lds[131072];
  const int tid = threadIdx.x, lane = tid & 63, wid = tid >> 6;
  const int wm = wid >> 2, wn = wid & 3;

  // T1: XCD-aware block swizzle (grid % 8 == 0 for all our shapes)
  const int nbx = N >> 8;
  const int cpx = gridDim.x >> 3;
  const int sid = ((int)blockIdx.x & 7) * cpx + ((int)blockIdx.x >> 3);
  const int bm = (sid / nbx) << 8;
  const int bn = (sid % nbx) << 8;

  // staging geometry: per wave 2 loads per half-tile (16KB half = 128 rows x 128B)
  int ga[2], gb[2];
  unsigned wdst[2];
#pragma unroll
  for (int c = 0; c < 2; ++c) {
    const int o = wid * 2048 + c * 1024 + lane * 16;   // linear offset in half-tile
    const int r = o >> 7;                              // row 0..127
    const int kb = (((o >> 4) & 7) ^ (r & 7)) * 16;    // inverse-swizzled k-byte
    ga[c] = (bm + r) * K * 2 + kb;
    gb[c] = (bn + r) * K * 2 + kb;
    wdst[c] = (unsigned)__builtin_amdgcn_readfirstlane(wid * 2048 + c * 1024);
  }
  const int hStep = 128 * K * 2;                       // half-tile global row step
  const char* Ag = (const char*)A;
  const char* Bg = (const char*)B;

  // frag-read offsets (chunk formula independent of frag index)
  const int rA = (wm * 128 + (lane & 15)) * 128;
  const int rB = 32768 + (wn * 64 + (lane & 15)) * 128;
  int ck[2];
#pragma unroll
  for (int s = 0; s < 2; ++s) ck[s] = ((s * 4 + (lane >> 4)) ^ (lane & 7)) * 16;

  f32x4 acc[8][4];
#pragma unroll
  for (int m = 0; m < 8; ++m)
#pragma unroll
    for (int n = 0; n < 4; ++n) acc[m][n] = 0.f;
  bf16x8 am[4][2], b0f[2][2], b1f[2][2];

#define STG(isB, half, t, buf) do { \
  _Pragma("unroll") for (int c_ = 0; c_ < 2; ++c_) { \
    const char* s_ = ((isB) ? Bg : Ag) + ((isB) ? gb[c_] : ga[c_]) + (half) * hStep + (t) * 128; \
    __builtin_amdgcn_global_load_lds(AS1C(s_), \
        AS3C(lds + ((buf) * 65536 + (isB) * 32768 + (half) * 16384 + wdst[c_])), 16, 0, 0); \
  } } while (0)

#define RDA(buf, mh) do { \
  _Pragma("unroll") for (int m_ = 0; m_ < 4; ++m_) \
  _Pragma("unroll") for (int s_ = 0; s_ < 2; ++s_) \
    am[m_][s_] = *(const bf16x8*)(lds + (buf) * 65536 + rA + ((mh) * 64 + m_ * 16) * 128 + ck[s_]); } while (0)

#define RDB(buf, nh, dst) do { \
  _Pragma("unroll") for (int n_ = 0; n_ < 2; ++n_) \
  _Pragma("unroll") for (int s_ = 0; s_ < 2; ++s_) \
    dst[n_][s_] = *(const bf16x8*)(lds + (buf) * 65536 + rB + ((nh) * 32 + n_ * 16) * 128 + ck[s_]); } while (0)

#define MM(mh, nh, bf) do { \
  __builtin_amdgcn_s_setprio(1); \
  _Pragma("unroll") for (int m_ = 0; m_ < 4; ++m_) \
  _Pragma("unroll") for (int n_ = 0; n_ < 2; ++n_) \
  _Pragma("unroll") for (int s_ = 0; s_ < 2; ++s_) \
    acc[(mh) * 4 + m_][(nh) * 2 + n_] = __builtin_amdgcn_mfma_f32_16x16x32_bf16( \
        am[m_][s_], bf[n_][s_], acc[(mh) * 4 + m_][(nh) * 2 + n_], 0, 0, 0); \
  __builtin_amdgcn_s_setprio(0); } while (0)

  const int nT = K >> 6, tmask = nT - 1, nIter = K >> 7;

  // prologue: buf0 tile0 {B0,B1,A0,A1}, buf1 tile1 {B0,B1}; wait 4 oldest halves
  STG(1, 0, 0, 0); STG(1, 1, 0, 0); STG(0, 0, 0, 0); STG(0, 1, 0, 0);
  STG(1, 0, 1, 1); STG(1, 1, 1, 1);
  WV4();
  BAR();

  for (int i = 0; i < nIter; ++i) {
    const int t1 = 2 * i + 1;
    const int t2 = (2 * i + 2) & tmask;
    const int t3 = (2 * i + 3) & tmask;
    // ph0: quad(0,0) buf0 | stage A0->buf1(t1)
    RDA(0, 0); RDB(0, 0, b0f); STG(0, 0, t1, 1); BAR(); WLG(); MM(0, 0, b0f); BAR();
    // ph1: quad(0,1) buf0 | stage A1->buf1(t1)
    RDB(0, 1, b1f); STG(0, 1, t1, 1); BAR(); WLG(); MM(0, 1, b1f); BAR();
    // ph2: quad(1,1) buf0 | stage B0->buf0(t2)
    RDA(0, 1); STG(1, 0, t2, 0); BAR(); WLG(); MM(1, 1, b1f); BAR();
    // ph3: quad(1,0) buf0 | stage B1->buf0(t2) | vmcnt gate for buf1(t1)
    STG(1, 1, t2, 0); WV4(); BAR(); MM(1, 0, b0f); BAR();
    // ph4: quad(0,0) buf1 | stage A0->buf0(t2)
    RDA(1, 0); RDB(1, 0, b0f); STG(0, 0, t2, 0); BAR(); WLG(); MM(0, 0, b0f); BAR();
    // ph5: quad(0,1) buf1 | stage A1->buf0(t2)
    RDB(1, 1, b1f); STG(0, 1, t2, 0); BAR(); WLG(); MM(0, 1, b1f); BAR();
    // ph6: quad(1,1) buf1 | stage B0->buf1(t3)
    RDA(1, 1); STG(1, 0, t3, 1); BAR(); WLG(); MM(1, 1, b1f); BAR();
    // ph7: quad(1,0) buf1 | stage B1->buf1(t3) | vmcnt gate for buf0(t2)
    STG(1, 1, t3, 1); WV4(); BAR(); MM(1, 0, b0f); BAR();
  }
  asm volatile("s_waitcnt vmcnt(0)" ::: "memory");

  // epilogue
  u16* Cb = (u16*)C;
  float* Cf = (float*)C;
#pragma unroll
  for (int n = 0; n < 4; ++n) {
    const int col = bn + wn * 64 + n * 16 + (lane & 15);
    const float bv = bias[col];
#pragma unroll
    for (int m = 0; m < 8; ++m) {
      const int rbase = bm + wm * 128 + m * 16 + (lane >> 4) * 4;
#pragma unroll
      for (int q = 0; q < 4; ++q) {
        float v = acc[m][n][q] + bv;
        if (RELU) v = fmaxf(v, 0.f);
        const long idx = (long)(rbase + q) * N + col;
        if (OUT_BF16) Cb[idx] = f2bf(v);
        else          Cf[idx] = v;
      }
    }
  }
#undef STG
#undef RDA
#undef RDB
#undef MM
}

// ---------------- V transpose: qkv V-block -> vt[g][h][c(64)][n(512)] ----------------
__global__ __launch_bounds__(256) void k_transpose_v(const u16* __restrict__ qkv,
                                                     u16* __restrict__ vt) {
  const int gh = blockIdx.x, g = gh >> 4, h = gh & 15;
  const int tid = threadIdx.x;
  __shared__ __align__(16) u16 tile[4096]; // [n(64)][c(64)] chunk-swizzled
  for (int nt = 0; nt < 8; ++nt) {
    const int n0 = nt * 64;
#pragma unroll
    for (int c = 0; c < 2; ++c) {
      const int ch = tid * 2 + c;           // 0..511
      const int n = ch >> 3;                // 0..63
      const int cc = ch & 7;                // logical 8-elem chunk in c-dim
      const uint4 v = *reinterpret_cast<const uint4*>(
          qkv + (long)(g * 512 + n0 + n) * 3072 + 2048 + h * 64 + cc * 8);
      const int phys = cc ^ (n & 7) ^ (n >> 3);
      *reinterpret_cast<uint4*>(tile + n * 64 + phys * 8) = v;
    }
    __syncthreads();
#pragma unroll
    for (int c = 0; c < 2; ++c) {
      const int ch = tid * 2 + c;
      const int crow = ch >> 3;             // head-col index 0..63
      const int noff = (ch & 7) * 8;
      union { u16 s[8]; uint4 u; } val;
#pragma unroll
      for (int i = 0; i < 8; ++i) {
        const int n = noff + i;
        const int phys = (crow >> 3) ^ (n & 7) ^ (n >> 3);
        val.s[i] = tile[n * 64 + phys * 8 + (crow & 7)];
      }
      *reinterpret_cast<uint4*>(vt + (long)(gh * 64 + crow) * 512 + n0 + noff) = val.u;
    }
    __syncthreads();
  }
}

// ---------------- fused attention ----------------
// grid: (8 q-blocks, 16 heads, 32 graphs), 256 threads (4 waves x 16 Q rows)
__global__ __launch_bounds__(256) void k_attn(const u16* __restrict__ qkv,
                                              const u16* __restrict__ vt,
                                              u16* __restrict__ out) {
  __shared__ __align__(16) char Ks[8192];       // [kvrow(64)][128B], chunk-XOR swizzled
  __shared__ __align__(16) char Vs[8192];       // [c(64)][128B kv], chunk-XOR swizzled
  __shared__ __align__(16) char Ps[4][2048];    // per-wave P [16][128B], swizzled
  const int tid = threadIdx.x, lane = tid & 63, wid = tid >> 6;
  const int qb = blockIdx.x, h = blockIdx.y, g = blockIdx.z;
  const int gh = g * 16 + h;
  const long grow0 = (long)g * 512;
  const char* qbase = (const char*)qkv;

  // Q fragments (row = lane&15 of this wave's 16-row strip)
  const long qrow = qb * 64 + wid * 16 + (lane & 15);
  bf16x8 qf[2];
#pragma unroll
  for (int kf = 0; kf < 2; ++kf) {
    const long go = (((grow0 + qrow) * 3072) + h * 64 + kf * 32 + (lane >> 4) * 8) * 2;
    qf[kf] = *reinterpret_cast<const bf16x8*>(qbase + go);
  }

  f32x4 oacc[4];
#pragma unroll
  for (int i = 0; i < 4; i++) oacc[i] = 0.f;
  float mrun[4], lrun[4];
#pragma unroll
  for (int q = 0; q < 4; q++) { mrun[q] = -3.0e38f; lrun[q] = 0.f; }

  const unsigned l0 = (unsigned)__builtin_amdgcn_readfirstlane(wid * 2048);
  const unsigned l1 = l0 + 1024;

  for (int it = 0; it < 8; ++it) {
    const int kv0 = it * 64;
    // stage K tile and V tile (source-side XOR swizzle, linear LDS dest)
#pragma unroll
    for (int c = 0; c < 2; ++c) {
      const int o = wid * 2048 + c * 1024 + lane * 16;
      const int row = o >> 7;
      const int pch = (o >> 4) & 7;
      const int lch = pch ^ (row & 7);
      const long gK = (((grow0 + kv0 + row) * 3072) + 1024 + h * 64 + lch * 8) * 2;
      __builtin_amdgcn_global_load_lds(AS1C(qbase + gK), AS3C(Ks + (c ? l1 : l0)), 16, 0, 0);
      const long gV = (((long)(gh * 64 + row)) * 512 + kv0 + lch * 8) * 2;
      __builtin_amdgcn_global_load_lds(AS1C((const char*)vt + gV), AS3C(Vs + (c ? l1 : l0)), 16, 0, 0);
    }
    __syncthreads();

    // S = Q K^T / 8  (4 tiles of 16 kv cols)
    f32x4 s[4];
#pragma unroll
    for (int nt = 0; nt < 4; ++nt) {
      const int krow = nt * 16 + (lane & 15);
      const int sw = krow & 7;
      const bf16x8 k0 = *reinterpret_cast<const bf16x8*>(Ks + krow * 128 + (((lane >> 4)) ^ sw) * 16);
      const bf16x8 k1 = *reinterpret_cast<const bf16x8*>(Ks + krow * 128 + (((lane >> 4) + 4) ^ sw) * 16);
      f32x4 t = 0.f;
      t = __builtin_amdgcn_mfma_f32_16x16x32_bf16(qf[0], k0, t, 0, 0, 0);
      t = __builtin_amdgcn_mfma_f32_16x16x32_bf16(qf[1], k1, t, 0, 0, 0);
#pragma unroll
      for (int q = 0; q < 4; q++) t[q] *= 0.125f;
      s[nt] = t;
    }

    // online softmax update (rows owned: (lane>>4)*4+q; cols across 16 lanes)
    float tmax[4];
#pragma unroll
    for (int q = 0; q < 4; q++)
      tmax[q] = fmaxf(fmaxf(s[0][q], s[1][q]), fmaxf(s[2][q], s[3][q]));
#pragma unroll
    for (int d = 1; d < 16; d <<= 1)
#pragma unroll
      for (int q = 0; q < 4; q++) tmax[q] = fmaxf(tmax[q], __shfl_xor(tmax[q], d));
    float sf[4];
#pragma unroll
    for (int q = 0; q < 4; q++) {
      const float mn = fmaxf(mrun[q], tmax[q]);
      sf[q] = __expf(mrun[q] - mn);
      mrun[q] = mn;
    }
    float rs[4] = {0.f, 0.f, 0.f, 0.f};
#pragma unroll
    for (int nt = 0; nt < 4; nt++)
#pragma unroll
      for (int q = 0; q < 4; q++) {
        const float p = __expf(s[nt][q] - mrun[q]);
        s[nt][q] = p;
        rs[q] += p;
      }
#pragma unroll
    for (int d = 1; d < 16; d <<= 1)
#pragma unroll
      for (int q = 0; q < 4; q++) rs[q] += __shfl_xor(rs[q], d);
#pragma unroll
    for (int q = 0; q < 4; q++) lrun[q] = lrun[q] * sf[q] + rs[q];
#pragma unroll
    for (int i = 0; i < 4; i++)
#pragma unroll
      for (int q = 0; q < 4; q++) oacc[i][q] *= sf[q];

    // P (bf16) -> per-wave LDS, swizzled
    char* pw = Ps[wid];
#pragma unroll
    for (int nt = 0; nt < 4; nt++) {
      const int cc = nt * 16 + (lane & 15);
#pragma unroll
      for (int q = 0; q < 4; q++) {
        const int r = (lane >> 4) * 4 + q;
        const int phys = (cc >> 3) ^ (r & 7);
        *(u16*)(pw + r * 128 + phys * 16 + (cc & 7) * 2) = f2bf(s[nt][q]);
      }
    }

    // O += P V
#pragma unroll
    for (int kf = 0; kf < 2; ++kf) {
      const int prow = lane & 15;
      const bf16x8 pa = *reinterpret_cast<const bf16x8*>(
          pw + prow * 128 + ((kf * 4 + (lane >> 4)) ^ (prow & 7)) * 16);
#pragma unroll
      for (int ot = 0; ot < 4; ++ot) {
        const int vr = ot * 16 + (lane & 15);
        const bf16x8 vb = *reinterpret_cast<const bf16x8*>(
            Vs + vr * 128 + ((kf * 4 + (lane >> 4)) ^ (vr & 7)) * 16);
        oacc[ot] = __builtin_amdgcn_mfma_f32_16x16x32_bf16(pa, vb, oacc[ot], 0, 0, 0);
      }
    }
    __syncthreads();
  }

  // epilogue: O / l -> bf16
#pragma unroll
  for (int ot = 0; ot < 4; ++ot) {
    const int col = h * 64 + ot * 16 + (lane & 15);
#pragma unroll
    for (int q = 0; q < 4; q++) {
      const long r = grow0 + qb * 64 + wid * 16 + (lane >> 4) * 4 + q;
      out[r * 1024 + col] = f2bf(oacc[ot][q] / lrun[q]);
    }
  }
}

// ---------------- residual + layernorm ----------------
template<bool EMIT_BF16>
__global__ __launch_bounds__(256) void k_ln(const float* __restrict__ A,
                                            const float* __restrict__ Bz,
                                            const float* __restrict__ gam,
                                            const float* __restrict__ bet,
                                            float* __restrict__ out_f,
                                            u16* __restrict__ out_b) {
  const int row = blockIdx.x;
  const int tid = threadIdx.x;
  const long base = (long)row * 1024;
  const float4 a = reinterpret_cast<const float4*>(A + base)[tid];
  const float4 b = reinterpret_cast<const float4*>(Bz + base)[tid];
  const float x0 = a.x + b.x, x1 = a.y + b.y, x2 = a.z + b.z, x3 = a.w + b.w;
  float s1 = x0 + x1 + x2 + x3;
  float s2 = x0 * x0 + x1 * x1 + x2 * x2 + x3 * x3;
#pragma unroll
  for (int d = 1; d < 64; d <<= 1) { s1 += __shfl_xor(s1, d); s2 += __shfl_xor(s2, d); }
  __shared__ float red[8];
  const int wid = tid >> 6, lane = tid & 63;
  if (lane == 0) { red[wid] = s1; red[4 + wid] = s2; }
  __syncthreads();
  s1 = red[0] + red[1] + red[2] + red[3];
  s2 = red[4] + red[5] + red[6] + red[7];
  const float mu = s1 * (1.f / 1024.f);
  const float var = s2 * (1.f / 1024.f) - mu * mu;
  const float rstd = rsqrtf(var + 1e-5f);
  const float4 gv = reinterpret_cast<const float4*>(gam)[tid];
  const float4 bv = reinterpret_cast<const float4*>(bet)[tid];
  float4 y;
  y.x = (x0 - mu) * rstd * gv.x + bv.x;
  y.y = (x1 - mu) * rstd * gv.y + bv.y;
  y.z = (x2 - mu) * rstd * gv.z + bv.z;
  y.w = (x3 - mu) * rstd * gv.w + bv.w;
  reinterpret_cast<float4*>(out_f + base)[tid] = y;
  if (EMIT_BF16) {
    ushort4 o;
    o.x = f2bf(y.x); o.y = f2bf(y.y); o.z = f2bf(y.z); o.w = f2bf(y.w);
    reinterpret_cast<ushort4*>(out_b + base)[tid] = o;
  }
}

// ---------------- launcher ----------------
extern "C" void kernel_launch(void* const* d_in, const int* in_sizes, int n_in,
                              void* d_out, int out_size, void* d_ws, size_t ws_size,
                              hipStream_t stream) {
  const float* h    = (const float*)d_in[0];
  const float* w_in = (const float*)d_in[1];
  const float* b_in = (const float*)d_in[2];
  const float* w_o  = (const float*)d_in[3];
  const float* b_o  = (const float*)d_in[4];
  const float* ln1g = (const float*)d_in[5];
  const float* ln1b = (const float*)d_in[6];
  const float* ln2g = (const float*)d_in[7];
  const float* ln2b = (const float*)d_in[8];
  const float* w1   = (const float*)d_in[9];
  const float* b1   = (const float*)d_in[10];
  const float* w2   = (const float*)d_in[11];
  const float* b2   = (const float*)d_in[12];

  const size_t WS_NEED = 184549376;
  if (ws_size < WS_NEED) {
    hipMemsetAsync(d_out, 0, (size_t)out_size * 4, stream);
    return;
  }

  char* W = (char*)d_ws;
  u16* h_bf     = (u16*)(W + 0);            // 33554432 B
  u16* w_in_bf  = (u16*)(W + 33554432);     // 6291456 B
  u16* w_out_bf = (u16*)(W + 39845888);     // 2097152 B
  u16* w1_bf    = (u16*)(W + 41943040);     // 4194304 B
  u16* w2_bf    = (u16*)(W + 46137344);     // 4194304 B
  u16* qkv      = (u16*)(W + 50331648);     // 100663296 B (dead after attn)
  u16* vt       = (u16*)(W + 150994944);    // 33554432 B  (dead after attn)
  float* x1     = (float*)(W + 50331648);   // 67108864 B (reuses qkv[0:67MB))
  u16* f1       = (u16*)(W + 117440512);    // 67108864 B (reuses qkv tail + vt)
  u16* attn_bf  = h_bf;
  u16* x1_bf    = h_bf;
  float* o32    = (float*)d_out;
  float* f2     = (float*)d_out;

  // bf16 conversions
  k_f2bf<<<dim3(16384), 256, 0, stream>>>(h, h_bf, 4194304);
  k_f2bf<<<dim3(3072),  256, 0, stream>>>(w_in, w_in_bf, 786432);
  k_f2bf<<<dim3(1024),  256, 0, stream>>>(w_o, w_out_bf, 262144);
  k_f2bf<<<dim3(2048),  256, 0, stream>>>(w1, w1_bf, 524288);
  k_f2bf<<<dim3(2048),  256, 0, stream>>>(w2, w2_bf, 524288);

  // qkv = h @ w_in^T + b_in   [16384, 3072] bf16   grid 64*12=768
  k_gemm256<true, false><<<dim3(768), 512, 0, stream>>>(h_bf, w_in_bf, b_in, (void*)qkv, 16384, 3072, 1024);
  // V transpose for attention B-operand
  k_transpose_v<<<dim3(512), 256, 0, stream>>>(qkv, vt);
  // fused attention -> attn_bf [16384, 1024] bf16
  k_attn<<<dim3(8, 16, 32), 256, 0, stream>>>(qkv, vt, attn_bf);
  // o = attn @ w_out^T + b_out  [16384, 1024] fp32 -> d_out   grid 64*4=256
  k_gemm256<false, false><<<dim3(256), 512, 0, stream>>>(attn_bf, w_out_bf, b_o, (void*)o32, 16384, 1024, 1024);
  // x1 = LN(h + o); also emit x1 as bf16 for FFN
  k_ln<true><<<dim3(16384), 256, 0, stream>>>(h, o32, ln1g, ln1b, x1, x1_bf);
  // f1 = relu(x1 @ w1^T + b1)  [16384, 2048] bf16   grid 64*8=512
  k_gemm256<true, true><<<dim3(512), 512, 0, stream>>>(x1_bf, w1_bf, b1, (void*)f1, 16384, 2048, 1024);
  // f2 = f1 @ w2^T + b2        [16384, 1024] fp32 -> d_out   grid 64*4=256
  k_gemm256<false, false><<<dim3(256), 512, 0, stream>>>(f1, w2_bf, b2, (void*)f2, 16384, 1024, 2048);
  // out = LN(x1 + f2)  (in-place on d_out)
  k_ln<false><<<dim3(16384), 256, 0, stream>>>(x1, f2, ln2g, ln2b, (float*)d_out, (u16*)nullptr);
}